// Round 8
// baseline (95.638 us; speedup 1.0000x reference)
//
#include <hip/hip_runtime.h>

#define T 128
#define L2E 1.4426950408889634f   // log2(e)
#define LN2F 0.6931471805599453f  // ln(2)
#define SENT -3.0e37f

// lane l <- lane l-1; lane 0 <- 0   (DPP wave_shr:1, bound_ctrl=0) -- verified r3-r7
__device__ __forceinline__ float shr1(float x) {
    return __int_as_float(__builtin_amdgcn_update_dpp(
        0, __float_as_int(x), 0x138, 0xF, 0xF, true));
}

template <int CTRL>
__device__ __forceinline__ float dppmax(float x) {
    float t = __int_as_float(__builtin_amdgcn_update_dpp(
        __float_as_int(x), __float_as_int(x), CTRL, 0xF, 0xF, false));
    return fmaxf(x, t);
}

struct RowF { float2 a, b, c, d; float s; };   // y'[8] f32 + sq

__launch_bounds__(256)
__global__ void sdtw_kernel(const float* __restrict__ X,
                            const float* __restrict__ Y,
                            float* __restrict__ out) {
    // Parity-split rows (r5-verified indexing): parity P, h in [0,195],
    // row r = 2h+P holds y-row j = 2h+P-126 (valid j in [0,127], else sentinel
    // => E=0). AoS stride 10 dwords (40 B): 8 y' + sq + pad; b64-aligned.
    __shared__ float lds[4 * 3920];
    const int lane = threadIdx.x & 63;
    const int w    = threadIdx.x >> 6;
    const int pair = blockIdx.x * 4 + w;   // 512 blocks * 4 waves = 2048 pairs
    const int a = pair >> 4;               // X index
    const int b = pair & 15;               // Y index

    float* E = lds + w * 3920;        // even-parity region (196 rows)
    float* O = E + 1960;              // odd-parity region

    // ---- stage Y[b]: y' = 2*L2E*y (f32), sq = -L2E*|y|^2; sentinels ----
    {
        const float* ybase = Y + (size_t)b * T * 8;
        for (int idx = lane; idx < 392; idx += 64) {
            int P = idx & 1, h = idx >> 1;
            int j = 2 * h + P - 126;
            float2 pa, pb, pc, pd;
            pa.x = 0.f; pa.y = 0.f; pb.x = 0.f; pb.y = 0.f;
            pc.x = 0.f; pc.y = 0.f; pd.x = 0.f; pd.y = 0.f;
            float sq = SENT;
            if (j >= 0 && j < T) {
                const float4* src = (const float4*)(ybase + j * 8);
                float4 y0 = src[0], y1 = src[1];
                float s = y0.x*y0.x + y0.y*y0.y + y0.z*y0.z + y0.w*y0.w
                        + y1.x*y1.x + y1.y*y1.y + y1.z*y1.z + y1.w*y1.w;
                const float c = 2.0f * L2E;
                pa.x = c*y0.x; pa.y = c*y0.y; pb.x = c*y0.z; pb.y = c*y0.w;
                pc.x = c*y1.x; pc.y = c*y1.y; pd.x = c*y1.z; pd.y = c*y1.w;
                sq = -L2E * s;
            }
            float* reg = (P ? O : E) + h * 10;
            *(float2*)(reg)     = pa;
            *(float2*)(reg + 2) = pb;
            *(float2*)(reg + 4) = pc;
            *(float2*)(reg + 6) = pd;
            reg[8] = sq;
        }
    }

    // ---- X rows 2l (even cell) and 2l+1 (odd cell), raw f32 ----
    float xe0,xe1,xe2,xe3,xe4,xe5,xe6,xe7, lsxe;
    float xo0,xo1,xo2,xo3,xo4,xo5,xo6,xo7, lsxo;
    {
        const float* xb = X + ((size_t)a * T + 2 * lane) * 8;
        const float4* s0p = (const float4*)xb;
        float4 v0 = s0p[0], v1 = s0p[1], u0 = s0p[2], u1 = s0p[3];
        xe0=v0.x; xe1=v0.y; xe2=v0.z; xe3=v0.w;
        xe4=v1.x; xe5=v1.y; xe6=v1.z; xe7=v1.w;
        lsxe = -L2E * (v0.x*v0.x+v0.y*v0.y+v0.z*v0.z+v0.w*v0.w
                      +v1.x*v1.x+v1.y*v1.y+v1.z*v1.z+v1.w*v1.w);
        xo0=u0.x; xo1=u0.y; xo2=u0.z; xo3=u0.w;
        xo4=u1.x; xo5=u1.y; xo6=u1.z; xo7=u1.w;
        lsxo = -L2E * (u0.x*u0.x+u0.y*u0.y+u0.z*u0.z+u0.w*u0.w
                      +u1.x*u1.x+u1.y*u1.y+u1.z*u1.z+u1.w*u1.w);
    }

    __syncthreads();

#define FETCH(SL, B, K) {                          \
    const float* q_ = (B) + (K) * 10;              \
    SL.a = *(const float2*)(q_);                   \
    SL.b = *(const float2*)(q_ + 2);               \
    SL.c = *(const float2*)(q_ + 4);               \
    SL.d = *(const float2*)(q_ + 6);               \
    SL.s = q_[8];                                  \
}

    // ---- prime ring: slot k holds row r = 126-2l+k (k=0..7) ----
    RowF s0, s1, s2, s3, s4, s5, s6, s7;
    const int hb0 = 63 - lane;
    {
        const float* Eh = E + hb0 * 10;
        const float* Oh = O + hb0 * 10;
        FETCH(s0, Eh, 0); FETCH(s1, Oh, 0);
        FETCH(s2, Eh, 1); FETCH(s3, Oh, 1);
        FETCH(s4, Eh, 2); FETCH(s5, Oh, 2);
        FETCH(s6, Eh, 3); FETCH(s7, Oh, 3);
    }
    const float* pe = E + (67 - lane) * 10;   // fetch base, even rows
    const float* po = O + (67 - lane) * 10;   // fetch base, odd rows

    // ---- p = 0: even cell (0,0) on lane 0 (sentinels zero the rest) ----
    float fe0 = 0.f, fo0 = 0.f, fo1 = 0.f, fe1;
    float sPrev = 0.f;   // carried shr1(PO1) from previous body
    int off = 90;
    {
        float t0 = fmaf(xe0, s0.a.x, lsxe);
        t0 = fmaf(xe1, s0.a.y, t0);
        t0 = fmaf(xe2, s0.b.x, t0);
        t0 = fmaf(xe3, s0.b.y, t0);
        float t1 = fmaf(xe4, s0.c.x, s0.s);
        t1 = fmaf(xe5, s0.c.y, t1);
        t1 = fmaf(xe6, s0.d.x, t1);
        t1 = fmaf(xe7, s0.d.y, t1);
        fe1 = __builtin_amdgcn_exp2f(t0 + t1) * 0x1p90f;
    }

    // BODY: PE1/PO1 = p-1 state, PE2/PO2 = p-2 state (overwritten).
    // RO = row for odd cell (y-row m-1), RE = row for even cell (y-row m).
#define BODY(PE1, PE2, PO1, PO2, RO, RE) {              \
    float ae0 = fmaf(xe0, RE.a.x, lsxe);                \
    ae0 = fmaf(xe1, RE.a.y, ae0);                       \
    ae0 = fmaf(xe2, RE.b.x, ae0);                       \
    ae0 = fmaf(xe3, RE.b.y, ae0);                       \
    float ae1 = fmaf(xe4, RE.c.x, RE.s);                \
    ae1 = fmaf(xe5, RE.c.y, ae1);                       \
    ae1 = fmaf(xe6, RE.d.x, ae1);                       \
    ae1 = fmaf(xe7, RE.d.y, ae1);                       \
    float Ee = __builtin_amdgcn_exp2f(ae0 + ae1);       \
    float ao0 = fmaf(xo0, RO.a.x, lsxo);                \
    ao0 = fmaf(xo1, RO.a.y, ao0);                       \
    ao0 = fmaf(xo2, RO.b.x, ao0);                       \
    ao0 = fmaf(xo3, RO.b.y, ao0);                       \
    float ao1 = fmaf(xo4, RO.c.x, RO.s);                \
    ao1 = fmaf(xo5, RO.c.y, ao1);                       \
    ao1 = fmaf(xo6, RO.d.x, ao1);                       \
    ao1 = fmaf(xo7, RO.d.y, ao1);                       \
    float Eo = __builtin_amdgcn_exp2f(ao0 + ao1);       \
    float sB = shr1(PO1);                               \
    float Se = Ee * ((sPrev + sB) + PE1);               \
    float So = Eo * ((PE2 + PE1) + PO1);                \
    sPrev = sB;                                         \
    PE2 = Se; PO2 = So;                                 \
}

#define RENORM() {                                                            \
    float mx = fmaxf(fmaxf(fe0, fe1), fmaxf(fo0, fo1));                       \
    mx = dppmax<0x111>(mx);  /* row_shr:1 */                                  \
    mx = dppmax<0x112>(mx);  /* row_shr:2 */                                  \
    mx = dppmax<0x114>(mx);  /* row_shr:4 */                                  \
    mx = dppmax<0x118>(mx);  /* row_shr:8 */                                  \
    int r0_ = __builtin_amdgcn_readlane(__float_as_int(mx), 15);              \
    int r1_ = __builtin_amdgcn_readlane(__float_as_int(mx), 31);              \
    int r2_ = __builtin_amdgcn_readlane(__float_as_int(mx), 47);              \
    int r3_ = __builtin_amdgcn_readlane(__float_as_int(mx), 63);              \
    int mb = max(max(r0_, r1_), max(r2_, r3_));                               \
    int e = ((mb >> 23) & 0xff) - 217;   /* renorm max to 2^90 */             \
    fe0 = ldexpf(fe0, -e); fe1 = ldexpf(fe1, -e);                             \
    fo0 = ldexpf(fo0, -e); fo1 = ldexpf(fo1, -e);                             \
    sPrev = ldexpf(sPrev, -e);   /* keep carried shift scale-coherent */      \
    off -= e;                                                                 \
}

    // ---- p = 1..248: 31 iterations of 8 bodies (r5-verified sequencing) ----
    for (int it = 0; it < 31; ++it) {
        BODY(fe1, fe0, fo1, fo0, s0, s1); FETCH(s0, pe, 0);   // fetch row p+7
        BODY(fe0, fe1, fo0, fo1, s1, s2); FETCH(s1, po, 0);
        BODY(fe1, fe0, fo1, fo0, s2, s3); FETCH(s2, pe, 1);
        BODY(fe0, fe1, fo0, fo1, s3, s4); FETCH(s3, po, 1);
        RENORM();
        BODY(fe1, fe0, fo1, fo0, s4, s5); FETCH(s4, pe, 2);
        BODY(fe0, fe1, fo0, fo1, s5, s6); FETCH(s5, po, 2);
        BODY(fe1, fe0, fo1, fo0, s6, s7); FETCH(s6, pe, 3);
        BODY(fe0, fe1, fo0, fo1, s7, s0); FETCH(s7, po, 3);
        RENORM();
        pe += 40; po += 40;
    }
    // p = 249..252 (+renorm), then tail p = 253, 254
    BODY(fe1, fe0, fo1, fo0, s0, s1); FETCH(s0, pe, 0);
    BODY(fe0, fe1, fo0, fo1, s1, s2); FETCH(s1, po, 0);
    BODY(fe1, fe0, fo1, fo0, s2, s3); FETCH(s2, pe, 1);
    BODY(fe0, fe1, fo0, fo1, s3, s4); FETCH(s3, po, 1);
    RENORM();
    BODY(fe1, fe0, fo1, fo0, s4, s5);   // p = 253
    BODY(fe0, fe1, fo0, fo1, s5, s6);   // p = 254 -> new So in fo1

    // final cell (127,127) = odd row of lane 63: R = (off - log2(S)) * ln2
    if (lane == 63)
        out[pair] = ((float)off - __builtin_amdgcn_logf(fo1)) * LN2F;
}

extern "C" void kernel_launch(void* const* d_in, const int* in_sizes, int n_in,
                              void* d_out, int out_size, void* d_ws, size_t ws_size,
                              hipStream_t stream) {
    const float* X = (const float*)d_in[0];   // (128,128,8) f32
    const float* Y = (const float*)d_in[1];   // (16,128,8) f32
    float* out = (float*)d_out;               // (128,16) f32
    sdtw_kernel<<<512, 256, 0, stream>>>(X, Y, out);
}